// Round 3
// baseline (177.533 us; speedup 1.0000x reference)
//
#include <hip/hip_runtime.h>
#include <stdint.h>

typedef unsigned short u16;
typedef __attribute__((ext_vector_type(8))) short short8;   // 8 x bf16 (4 VGPRs)
typedef __attribute__((ext_vector_type(4))) short short4v;  // 4 x bf16
typedef __attribute__((ext_vector_type(4))) float f32x4;

#define AS1 __attribute__((address_space(1)))
#define AS3 __attribute__((address_space(3)))

__device__ __forceinline__ u16 f2bf(float f) {
  uint32_t x = __builtin_bit_cast(uint32_t, f);
  uint32_t r = (x + 0x7fffu + ((x >> 16) & 1u)) >> 16;   // RNE
  return (u16)r;
}
__device__ __forceinline__ float bf2f(u16 u) {
  return __builtin_bit_cast(float, (uint32_t)u << 16);
}

// ---------------- pack: fp32 -> bf16 conversions + weight concat ----------------
__device__ __forceinline__ void conv8(const float* __restrict__ s, u16* __restrict__ d, float sc) {
  float4 a = *(const float4*)s;
  float4 b = *(const float4*)(s + 4);
  union { u16 u[8]; uint4 v; } pk;
  pk.u[0] = f2bf(a.x * sc); pk.u[1] = f2bf(a.y * sc); pk.u[2] = f2bf(a.z * sc); pk.u[3] = f2bf(a.w * sc);
  pk.u[4] = f2bf(b.x * sc); pk.u[5] = f2bf(b.y * sc); pk.u[6] = f2bf(b.z * sc); pk.u[7] = f2bf(b.w * sc);
  *(uint4*)d = pk.v;
}
__device__ __forceinline__ void copy8f(const float* __restrict__ s, float* __restrict__ d, float sc) {
  float4 a = *(const float4*)s;
  float4 b = *(const float4*)(s + 4);
  a.x *= sc; a.y *= sc; a.z *= sc; a.w *= sc;
  b.x *= sc; b.y *= sc; b.z *= sc; b.w *= sc;
  *(float4*)d = a; *(float4*)(d + 4) = b;
}

__global__ void pack_kernel(const float* __restrict__ X,
                            const float* __restrict__ Wq, const float* __restrict__ bq,
                            const float* __restrict__ Wk, const float* __restrict__ bk,
                            const float* __restrict__ Wv, const float* __restrict__ bv,
                            const float* __restrict__ Wo,
                            u16* __restrict__ Xbf, u16* __restrict__ Wcat,
                            u16* __restrict__ Wobf, float* __restrict__ bcat) {
  int t = blockIdx.x * blockDim.x + threadIdx.x;
  if (t < 524288) { conv8(X + (size_t)t * 8, Xbf + (size_t)t * 8, 1.f); return; }
  t -= 524288;
  if (t < 131072) { conv8(Wq + (size_t)t * 8, Wcat + (size_t)t * 8, 0.125f); return; }   // fold D^-0.5
  t -= 131072;
  if (t < 131072) { conv8(Wk + (size_t)t * 8, Wcat + 1048576 + (size_t)t * 8, 1.f); return; }
  t -= 131072;
  if (t < 131072) { conv8(Wv + (size_t)t * 8, Wcat + 2097152 + (size_t)t * 8, 1.f); return; }
  t -= 131072;
  if (t < 131072) { conv8(Wo + (size_t)t * 8, Wobf + (size_t)t * 8, 1.f); return; }
  t -= 131072;
  if (t < 128) { copy8f(bq + t * 8, bcat + t * 8, 0.125f); return; }
  t -= 128;
  if (t < 128) { copy8f(bk + t * 8, bcat + 1024 + t * 8, 1.f); return; }
  t -= 128;
  if (t < 128) { copy8f(bv + t * 8, bcat + 2048 + t * 8, 1.f); return; }
}

// ---------------- bf16 GEMM, BK=64, XOR-swizzled LDS: C = A * Bt^T + bias ----------------
// LDS layout: tile [128 rows][8 x 16B-blocks]; block cb of row r stored at slot cb^(r&7).
// global_load_lds forces contiguous LDS (base + lane*16B), so the swizzle is applied on the
// GLOBAL source address side (any per-lane address is legal). Frag reads then hit 8 distinct
// bank-quads across the 16 rows of a quad-group -> 2-way max (free, m136), vs 8-way before.
template <bool OUT_BF16>
__global__ __launch_bounds__(256)
void gemm_bt(const u16* __restrict__ A, const u16* __restrict__ Bt,
             const float* __restrict__ bias, u16* __restrict__ Cbf,
             float* __restrict__ Cf, int M, int N, int K) {
  __shared__ u16 As[128 * 64];
  __shared__ u16 Bs[128 * 64];
  const int wv = threadIdx.x >> 6;
  const int lane = threadIdx.x & 63;
  const int bm = blockIdx.x, bn = blockIdx.y;
  const int wm = wv >> 1, wn = wv & 1;          // 2x2 wave grid, 64x64 per wave
  const int lrow = lane & 15, quad = lane >> 4;

  f32x4 acc[4][4];
#pragma unroll
  for (int i = 0; i < 4; ++i)
#pragma unroll
    for (int j = 0; j < 4; ++j) acc[i][j] = (f32x4){0.f, 0.f, 0.f, 0.f};

  const long arow = (long)bm * 128;
  const long brow = (long)bn * 128;
  // staging decomposition (per global_load_lds, 64 lanes x 16B): within segment s,
  // lane covers LDS block blk = s*64+lane -> row = s*8 + (lane>>3), slot = lane&7.
  // data for slot: cb = slot ^ (row&7) = (lane&7) ^ ((lane>>3)&7).
  const int srow = lane >> 3;
  const int scol = ((lane & 7) ^ (srow & 7)) * 8;

  for (int k0 = 0; k0 < K; k0 += 64) {
    __syncthreads();
#pragma unroll
    for (int it = 0; it < 4; ++it) {
      const int s = wv * 4 + it;                 // 16 x 1KiB segments per 16KiB tile
      const int r = s * 8 + srow;
      const u16* ga = A + (arow + r) * K + k0 + scol;
      const u16* gb = Bt + (brow + r) * K + k0 + scol;
      u16* la = (u16*)As + s * 512;              // wave-uniform LDS base; HW adds lane*16B
      u16* lb = (u16*)Bs + s * 512;
      __builtin_amdgcn_global_load_lds((AS1 void*)ga, (AS3 void*)la, 16, 0, 0);
      __builtin_amdgcn_global_load_lds((AS1 void*)gb, (AS3 void*)lb, 16, 0, 0);
    }
    __syncthreads();

#pragma unroll
    for (int h = 0; h < 2; ++h) {
      const int swz = ((h * 4 + quad) ^ (lrow & 7)) * 8;   // swizzled 16B slot for k-half h
      short8 af[4], bfr[4];
#pragma unroll
      for (int mi = 0; mi < 4; ++mi)
        af[mi] = *(const short8*)(As + (wm * 64 + mi * 16 + lrow) * 64 + swz);
#pragma unroll
      for (int ni = 0; ni < 4; ++ni)
        bfr[ni] = *(const short8*)(Bs + (wn * 64 + ni * 16 + lrow) * 64 + swz);
#pragma unroll
      for (int mi = 0; mi < 4; ++mi)
#pragma unroll
        for (int ni = 0; ni < 4; ++ni)
          acc[mi][ni] = __builtin_amdgcn_mfma_f32_16x16x32_bf16(af[mi], bfr[ni], acc[mi][ni], 0, 0, 0);
    }
  }

  // epilogue: C/D layout col=lane&15, row=quad*4+r (verified m89/m91)
#pragma unroll
  for (int mi = 0; mi < 4; ++mi) {
#pragma unroll
    for (int ni = 0; ni < 4; ++ni) {
      const int col = bn * 128 + wn * 64 + ni * 16 + lrow;
      const float bv = bias[col];
#pragma unroll
      for (int r = 0; r < 4; ++r) {
        const int row = bm * 128 + wm * 64 + mi * 16 + quad * 4 + r;
        const float v = acc[mi][ni][r] + bv;
        if constexpr (OUT_BF16) Cbf[(long)row * N + col] = f2bf(v);
        else Cf[(long)row * N + col] = v;
      }
    }
  }
}

// ---------------- MFMA windowed attention: one wave per (b,h,chunk) ----------------
// allowed keys for query i: [max(0,i-25), chunk_end)  (contiguous, <=35)
#define NCH 205  // ceil(2048/10)
#define VT_STRIDE 68   // u16; 136B rows: 8B aligned (b64 reads), 2-way read conflict only
#define PB_STRIDE 72   // u16; 144B rows: 16B aligned (b128 reads)
#define WAVE_LDS (64 * VT_STRIDE + 16 * PB_STRIDE)   // 5504 u16 = 11008 B

__global__ __launch_bounds__(256)
void attn_kernel(const u16* __restrict__ QKV, u16* __restrict__ ctx) {
  __shared__ __align__(16) u16 lds[4 * WAVE_LDS];
  const int wv = threadIdx.x >> 6;
  const int lane = threadIdx.x & 63;
  u16* Vt = lds + wv * WAVE_LDS;      // [64 d][68] bf16 (V^T, zero-padded)
  u16* Pb = Vt + 64 * VT_STRIDE;      // [16 q][72] bf16 (P in row-major for A-frag)

  const int n = lane & 15, quad = lane >> 4;

  const int gw = blockIdx.x * 4 + wv;           // 6560 waves exactly
  const int b = gw / (16 * NCH);
  int rem = gw - b * 16 * NCH;
  const int h = rem / NCH;
  const int c = rem - h * NCH;
  const int cs = c * 10;
  const int nq = min(10, 2048 - cs);
  const int w0 = max(cs - 25, 0);
  const int L = cs + nq - w0;                   // window length <= 35

  const long base = ((long)b * 2048) * 3072 + (long)h * 64;

  // zero Vt and Pb (so MFMA pad regions multiply as 0, no NaN risk)
  for (int idx = lane; idx < (64 * VT_STRIDE) / 8; idx += 64)
    *(uint4*)(Vt + idx * 8) = (uint4){0, 0, 0, 0};
  for (int idx = lane; idx < (16 * PB_STRIDE) / 8; idx += 64)
    *(uint4*)(Pb + idx * 8) = (uint4){0, 0, 0, 0};

  // stage V transposed: Vt[d=lane][j] = V[w0+j][d]  (coalesced 128B global reads)
  for (int j = 0; j < L; ++j)
    Vt[lane * VT_STRIDE + j] = QKV[base + (long)(w0 + j) * 3072 + 2048 + lane];

  // ---- scores = Q * K^T via MFMA (M=16 pad, N=48 = 3 tiles, K=64) ----
  // A-frag: lane holds Q[m=n][k=quad*8+idx+32*s]  (direct 16B global loads)
  const int mclamp = min(n, nq - 1);
  const long qrow = base + (long)(cs + mclamp) * 3072;
  short8 aq0 = *(const short8*)(QKV + qrow + quad * 8);
  short8 aq1 = *(const short8*)(QKV + qrow + 32 + quad * 8);

  f32x4 sc[3];
#pragma unroll
  for (int t = 0; t < 3; ++t) {
    const int jj = min(16 * t + n, L - 1);      // clamp: garbage masked later
    const long krow = base + (long)(w0 + jj) * 3072 + 1024;
    short8 bk0 = *(const short8*)(QKV + krow + quad * 8);
    short8 bk1 = *(const short8*)(QKV + krow + 32 + quad * 8);
    f32x4 z = (f32x4){0.f, 0.f, 0.f, 0.f};
    z = __builtin_amdgcn_mfma_f32_16x16x32_bf16(aq0, bk0, z, 0, 0, 0);
    sc[t] = __builtin_amdgcn_mfma_f32_16x16x32_bf16(aq1, bk1, z, 0, 0, 0);
  }

  // ---- softmax in C-layout (col = 16t+n, row = quad*4+r), write P to LDS bf16 ----
#pragma unroll
  for (int r = 0; r < 4; ++r) {
    const int i = cs + quad * 4 + r;            // query index (rows >= nq are garbage, unstored)
    const int jlo = max(i - 25, 0) - w0;
    float v0 = (n >= jlo && n < L)      ? sc[0][r] : -1e30f;
    float v1 = (16 + n >= jlo && 16 + n < L) ? sc[1][r] : -1e30f;
    float v2 = (32 + n >= jlo && 32 + n < L) ? sc[2][r] : -1e30f;
    float m = fmaxf(v0, fmaxf(v1, v2));
#pragma unroll
    for (int off = 8; off > 0; off >>= 1) m = fmaxf(m, __shfl_xor(m, off));  // 16-lane row groups
    float p0 = __expf(v0 - m), p1 = __expf(v1 - m), p2 = __expf(v2 - m);
    float sum = p0 + p1 + p2;
#pragma unroll
    for (int off = 8; off > 0; off >>= 1) sum += __shfl_xor(sum, off);
    const float inv = 1.f / sum;
    u16* prow = Pb + (quad * 4 + r) * PB_STRIDE;
    prow[n]      = f2bf(p0 * inv);
    prow[16 + n] = f2bf(p1 * inv);
    prow[32 + n] = f2bf(p2 * inv);
  }
  // same-wave LDS RAW: DS pipe in-order per wave; compiler inserts lgkmcnt waits

  // ---- O = P * V via MFMA (M=16, N=64 = 4 tiles, K=64: j padded with zeros) ----
  short8 ap0 = *(const short8*)(Pb + n * PB_STRIDE + quad * 8);        // k = quad*8+idx
  short8 ap1 = *(const short8*)(Pb + n * PB_STRIDE + 32 + quad * 8);   // k = 32+quad*8+idx (zeros >= L)
  f32x4 o[4];
#pragma unroll
  for (int dt = 0; dt < 4; ++dt) {
    const u16* vrow = Vt + (dt * 16 + n) * VT_STRIDE;   // Bt[n=d][k=j] = V^T
    short4v l0 = *(const short4v*)(vrow + quad * 8);
    short4v h0 = *(const short4v*)(vrow + quad * 8 + 4);
    short4v l1 = *(const short4v*)(vrow + 32 + quad * 8);
    short4v h1 = *(const short4v*)(vrow + 32 + quad * 8 + 4);
    short8 bv0 = __builtin_shufflevector(l0, h0, 0, 1, 2, 3, 4, 5, 6, 7);
    short8 bv1 = __builtin_shufflevector(l1, h1, 0, 1, 2, 3, 4, 5, 6, 7);
    f32x4 z = (f32x4){0.f, 0.f, 0.f, 0.f};
    z = __builtin_amdgcn_mfma_f32_16x16x32_bf16(ap0, bv0, z, 0, 0, 0);
    o[dt] = __builtin_amdgcn_mfma_f32_16x16x32_bf16(ap1, bv1, z, 0, 0, 0);
  }

  // ---- store (C-layout: col = d within tile, row = quad*4+r) ----
#pragma unroll
  for (int dt = 0; dt < 4; ++dt) {
#pragma unroll
    for (int r = 0; r < 4; ++r) {
      const int row = quad * 4 + r;
      if (row < nq)
        ctx[((long)b * 2048 + cs + row) * 1024 + h * 64 + dt * 16 + n] = f2bf(o[dt][r]);
    }
  }
}

extern "C" void kernel_launch(void* const* d_in, const int* in_sizes, int n_in,
                              void* d_out, int out_size, void* d_ws, size_t ws_size,
                              hipStream_t stream) {
  const float* X  = (const float*)d_in[0];
  const float* Wq = (const float*)d_in[1];
  const float* bq = (const float*)d_in[2];
  const float* Wk = (const float*)d_in[3];
  const float* bk = (const float*)d_in[4];
  const float* Wv = (const float*)d_in[5];
  const float* bv = (const float*)d_in[6];
  const float* Wo = (const float*)d_in[7];
  const float* bo = (const float*)d_in[8];
  float* out = (float*)d_out;

  char* ws = (char*)d_ws;
  u16* Xbf   = (u16*)(ws);                  // [4096,1024] bf16   8,388,608 B
  u16* Wcat  = (u16*)(ws + 8388608);        // [3072,1024] bf16   6,291,456 B
  u16* Wobf  = (u16*)(ws + 14680064);       // [1024,1024] bf16   2,097,152 B
  float* bcat = (float*)(ws + 16777216);    // [3072] f32            12,288 B
  u16* QKV   = (u16*)(ws + 16789504);       // [4096,3072] bf16  25,165,824 B
  u16* ctx   = (u16*)(ws + 41955328);       // [4096,1024] bf16   8,388,608 B

  pack_kernel<<<4098, 256, 0, stream>>>(X, Wq, bq, Wk, bk, Wv, bv, Wo, Xbf, Wcat, Wobf, bcat);
  gemm_bt<true ><<<dim3(32, 24), 256, 0, stream>>>(Xbf, Wcat, bcat, QKV, nullptr, 4096, 3072, 1024);
  attn_kernel<<<1640, 256, 0, stream>>>(QKV, ctx);
  gemm_bt<false><<<dim3(32, 8), 256, 0, stream>>>(ctx, Wobf, bo, nullptr, out, 4096, 1024, 1024);
}

// Round 4
// 176.586 us; speedup vs baseline: 1.0054x; 1.0054x over previous
//
#include <hip/hip_runtime.h>
#include <stdint.h>

typedef unsigned short u16;
typedef __attribute__((ext_vector_type(8))) short short8;   // 8 x bf16 (4 VGPRs)
typedef __attribute__((ext_vector_type(4))) short short4v;  // 4 x bf16
typedef __attribute__((ext_vector_type(4))) float f32x4;

#define AS1 __attribute__((address_space(1)))
#define AS3 __attribute__((address_space(3)))

__device__ __forceinline__ u16 f2bf(float f) {
  uint32_t x = __builtin_bit_cast(uint32_t, f);
  uint32_t r = (x + 0x7fffu + ((x >> 16) & 1u)) >> 16;   // RNE
  return (u16)r;
}
__device__ __forceinline__ float bf2f(u16 u) {
  return __builtin_bit_cast(float, (uint32_t)u << 16);
}

// ---------------- pack: fp32 -> bf16 conversions + weight concat ----------------
__device__ __forceinline__ void conv8(const float* __restrict__ s, u16* __restrict__ d, float sc) {
  float4 a = *(const float4*)s;
  float4 b = *(const float4*)(s + 4);
  union { u16 u[8]; uint4 v; } pk;
  pk.u[0] = f2bf(a.x * sc); pk.u[1] = f2bf(a.y * sc); pk.u[2] = f2bf(a.z * sc); pk.u[3] = f2bf(a.w * sc);
  pk.u[4] = f2bf(b.x * sc); pk.u[5] = f2bf(b.y * sc); pk.u[6] = f2bf(b.z * sc); pk.u[7] = f2bf(b.w * sc);
  *(uint4*)d = pk.v;
}
__device__ __forceinline__ void copy8f(const float* __restrict__ s, float* __restrict__ d, float sc) {
  float4 a = *(const float4*)s;
  float4 b = *(const float4*)(s + 4);
  a.x *= sc; a.y *= sc; a.z *= sc; a.w *= sc;
  b.x *= sc; b.y *= sc; b.z *= sc; b.w *= sc;
  *(float4*)d = a; *(float4*)(d + 4) = b;
}

__global__ void pack_kernel(const float* __restrict__ X,
                            const float* __restrict__ Wq, const float* __restrict__ bq,
                            const float* __restrict__ Wk, const float* __restrict__ bk,
                            const float* __restrict__ Wv, const float* __restrict__ bv,
                            const float* __restrict__ Wo,
                            u16* __restrict__ Xbf, u16* __restrict__ Wcat,
                            u16* __restrict__ Wobf, float* __restrict__ bcat) {
  int t = blockIdx.x * blockDim.x + threadIdx.x;
  if (t < 524288) { conv8(X + (size_t)t * 8, Xbf + (size_t)t * 8, 1.f); return; }
  t -= 524288;
  if (t < 131072) { conv8(Wq + (size_t)t * 8, Wcat + (size_t)t * 8, 0.125f); return; }   // fold D^-0.5
  t -= 131072;
  if (t < 131072) { conv8(Wk + (size_t)t * 8, Wcat + 1048576 + (size_t)t * 8, 1.f); return; }
  t -= 131072;
  if (t < 131072) { conv8(Wv + (size_t)t * 8, Wcat + 2097152 + (size_t)t * 8, 1.f); return; }
  t -= 131072;
  if (t < 131072) { conv8(Wo + (size_t)t * 8, Wobf + (size_t)t * 8, 1.f); return; }
  t -= 131072;
  if (t < 128) { copy8f(bq + t * 8, bcat + t * 8, 0.125f); return; }
  t -= 128;
  if (t < 128) { copy8f(bk + t * 8, bcat + 1024 + t * 8, 1.f); return; }
  t -= 128;
  if (t < 128) { copy8f(bv + t * 8, bcat + 2048 + t * 8, 1.f); return; }
}

// ---------------- bf16 GEMM, BK=32 (round-2 structure) + XOR-swizzled LDS ----------------
// Tile row = 32 elems = 4 x 16B slots. Slot q of row r stored at slot q^((r>>1)&3).
// global_load_lds forces LDS dest = base + lane*16B, so the swizzle is applied to the GLOBAL
// source address (4-lane groups still cover one contiguous 64B row segment -> same cache lines).
// Frag ds_read_b128: 16 lanes of a quad-group hit each bank-position exactly 2x (2-way = free,
// m136) instead of 8-way as in round 2 (3.1M conflict-cycles).
template <bool OUT_BF16>
__global__ __launch_bounds__(256)
void gemm_bt(const u16* __restrict__ A, const u16* __restrict__ Bt,
             const float* __restrict__ bias, u16* __restrict__ Cbf,
             float* __restrict__ Cf, int M, int N, int K) {
  __shared__ u16 As[128 * 32];
  __shared__ u16 Bs[128 * 32];
  const int wv = threadIdx.x >> 6;
  const int lane = threadIdx.x & 63;
  const int bm = blockIdx.x, bn = blockIdx.y;
  const int wm = wv >> 1, wn = wv & 1;          // 2x2 wave grid, 64x64 per wave
  const int lrow = lane & 15, quad = lane >> 4;

  f32x4 acc[4][4];
#pragma unroll
  for (int i = 0; i < 4; ++i)
#pragma unroll
    for (int j = 0; j < 4; ++j) acc[i][j] = (f32x4){0.f, 0.f, 0.f, 0.f};

  const long arow = (long)bm * 128;
  const long brow = (long)bn * 128;
  // staging decomposition: segment s covers rows s*16..s*16+15; lane -> row srow = lane>>2,
  // LDS slot sl = lane&3; source col-block cb = sl ^ ((row>>1)&3) = (lane&3)^((lane>>3)&3)
  // (s*16 contributes 0 mod 4 after >>1).
  const int srow = lane >> 2;
  const int scol = ((lane & 3) ^ ((lane >> 3) & 3)) * 8;   // element offset in row
  const int swz = (quad ^ ((lrow >> 1) & 3)) * 8;          // frag-read slot offset (elements)

  for (int k0 = 0; k0 < K; k0 += 32) {
    __syncthreads();
#pragma unroll
    for (int it = 0; it < 2; ++it) {
      const int s = wv * 2 + it;                 // 8 x 1KiB segments per 8KiB tile
      const int r = s * 16 + srow;
      const u16* ga = A + (arow + r) * K + k0 + scol;
      const u16* gb = Bt + (brow + r) * K + k0 + scol;
      u16* la = (u16*)As + s * 512;              // wave-uniform LDS base; HW adds lane*16B
      u16* lb = (u16*)Bs + s * 512;
      __builtin_amdgcn_global_load_lds((AS1 void*)ga, (AS3 void*)la, 16, 0, 0);
      __builtin_amdgcn_global_load_lds((AS1 void*)gb, (AS3 void*)lb, 16, 0, 0);
    }
    __syncthreads();

    short8 af[4], bfr[4];
#pragma unroll
    for (int mi = 0; mi < 4; ++mi)
      af[mi] = *(const short8*)(As + (wm * 64 + mi * 16 + lrow) * 32 + swz);
#pragma unroll
    for (int ni = 0; ni < 4; ++ni)
      bfr[ni] = *(const short8*)(Bs + (wn * 64 + ni * 16 + lrow) * 32 + swz);
#pragma unroll
    for (int mi = 0; mi < 4; ++mi)
#pragma unroll
      for (int ni = 0; ni < 4; ++ni)
        acc[mi][ni] = __builtin_amdgcn_mfma_f32_16x16x32_bf16(af[mi], bfr[ni], acc[mi][ni], 0, 0, 0);
  }

  // epilogue: C/D layout col=lane&15, row=quad*4+r (verified m89/m91)
#pragma unroll
  for (int mi = 0; mi < 4; ++mi) {
#pragma unroll
    for (int ni = 0; ni < 4; ++ni) {
      const int col = bn * 128 + wn * 64 + ni * 16 + lrow;
      const float bv = bias[col];
#pragma unroll
      for (int r = 0; r < 4; ++r) {
        const int row = bm * 128 + wm * 64 + mi * 16 + quad * 4 + r;
        const float v = acc[mi][ni][r] + bv;
        if constexpr (OUT_BF16) Cbf[(long)row * N + col] = f2bf(v);
        else Cf[(long)row * N + col] = v;
      }
    }
  }
}

// ---------------- MFMA windowed attention: one wave per (b,h,chunk) ----------------
// allowed keys for query i: [max(0,i-25), chunk_end)  (contiguous, <=35)
#define NCH 205  // ceil(2048/10)
#define VT_STRIDE 68   // u16; 136B rows: 8B aligned (b64 reads), 2-way read conflict only
#define PB_STRIDE 72   // u16; 144B rows: 16B aligned (b128 reads)
#define WAVE_LDS (64 * VT_STRIDE + 16 * PB_STRIDE)   // 5504 u16 = 11008 B

__global__ __launch_bounds__(256)
void attn_kernel(const u16* __restrict__ QKV, u16* __restrict__ ctx) {
  __shared__ __align__(16) u16 lds[4 * WAVE_LDS];
  const int wv = threadIdx.x >> 6;
  const int lane = threadIdx.x & 63;
  u16* Vt = lds + wv * WAVE_LDS;      // [64 d][68] bf16 (V^T, zero-padded)
  u16* Pb = Vt + 64 * VT_STRIDE;      // [16 q][72] bf16 (P in row-major for A-frag)

  const int n = lane & 15, quad = lane >> 4;

  const int gw = blockIdx.x * 4 + wv;           // 6560 waves exactly
  const int b = gw / (16 * NCH);
  int rem = gw - b * 16 * NCH;
  const int h = rem / NCH;
  const int c = rem - h * NCH;
  const int cs = c * 10;
  const int nq = min(10, 2048 - cs);
  const int w0 = max(cs - 25, 0);
  const int L = cs + nq - w0;                   // window length <= 35

  const long base = ((long)b * 2048) * 3072 + (long)h * 64;

  // zero Vt and Pb (so MFMA pad regions multiply as 0, no NaN risk)
  for (int idx = lane; idx < (64 * VT_STRIDE) / 8; idx += 64)
    *(uint4*)(Vt + idx * 8) = (uint4){0, 0, 0, 0};
  for (int idx = lane; idx < (16 * PB_STRIDE) / 8; idx += 64)
    *(uint4*)(Pb + idx * 8) = (uint4){0, 0, 0, 0};

  // stage V transposed: Vt[d=lane][j] = V[w0+j][d]  (coalesced 128B global reads)
  for (int j = 0; j < L; ++j)
    Vt[lane * VT_STRIDE + j] = QKV[base + (long)(w0 + j) * 3072 + 2048 + lane];

  // ---- scores = Q * K^T via MFMA (M=16 pad, N=48 = 3 tiles, K=64) ----
  // A-frag: lane holds Q[m=n][k=quad*8+idx+32*s]  (direct 16B global loads)
  const int mclamp = min(n, nq - 1);
  const long qrow = base + (long)(cs + mclamp) * 3072;
  short8 aq0 = *(const short8*)(QKV + qrow + quad * 8);
  short8 aq1 = *(const short8*)(QKV + qrow + 32 + quad * 8);

  f32x4 sc[3];
#pragma unroll
  for (int t = 0; t < 3; ++t) {
    const int jj = min(16 * t + n, L - 1);      // clamp: garbage masked later
    const long krow = base + (long)(w0 + jj) * 3072 + 1024;
    short8 bk0 = *(const short8*)(QKV + krow + quad * 8);
    short8 bk1 = *(const short8*)(QKV + krow + 32 + quad * 8);
    f32x4 z = (f32x4){0.f, 0.f, 0.f, 0.f};
    z = __builtin_amdgcn_mfma_f32_16x16x32_bf16(aq0, bk0, z, 0, 0, 0);
    sc[t] = __builtin_amdgcn_mfma_f32_16x16x32_bf16(aq1, bk1, z, 0, 0, 0);
  }

  // ---- softmax in C-layout (col = 16t+n, row = quad*4+r), write P to LDS bf16 ----
#pragma unroll
  for (int r = 0; r < 4; ++r) {
    const int i = cs + quad * 4 + r;            // query index (rows >= nq are garbage, unstored)
    const int jlo = max(i - 25, 0) - w0;
    float v0 = (n >= jlo && n < L)      ? sc[0][r] : -1e30f;
    float v1 = (16 + n >= jlo && 16 + n < L) ? sc[1][r] : -1e30f;
    float v2 = (32 + n >= jlo && 32 + n < L) ? sc[2][r] : -1e30f;
    float m = fmaxf(v0, fmaxf(v1, v2));
#pragma unroll
    for (int off = 8; off > 0; off >>= 1) m = fmaxf(m, __shfl_xor(m, off));  // 16-lane row groups
    float p0 = __expf(v0 - m), p1 = __expf(v1 - m), p2 = __expf(v2 - m);
    float sum = p0 + p1 + p2;
#pragma unroll
    for (int off = 8; off > 0; off >>= 1) sum += __shfl_xor(sum, off);
    const float inv = 1.f / sum;
    u16* prow = Pb + (quad * 4 + r) * PB_STRIDE;
    prow[n]      = f2bf(p0 * inv);
    prow[16 + n] = f2bf(p1 * inv);
    prow[32 + n] = f2bf(p2 * inv);
  }
  // same-wave LDS RAW: DS pipe in-order per wave; compiler inserts lgkmcnt waits

  // ---- O = P * V via MFMA (M=16, N=64 = 4 tiles, K=64: j padded with zeros) ----
  short8 ap0 = *(const short8*)(Pb + n * PB_STRIDE + quad * 8);        // k = quad*8+idx
  short8 ap1 = *(const short8*)(Pb + n * PB_STRIDE + 32 + quad * 8);   // k = 32+quad*8+idx (zeros >= L)
  f32x4 o[4];
#pragma unroll
  for (int dt = 0; dt < 4; ++dt) {
    const u16* vrow = Vt + (dt * 16 + n) * VT_STRIDE;   // Bt[n=d][k=j] = V^T
    short4v l0 = *(const short4v*)(vrow + quad * 8);
    short4v h0 = *(const short4v*)(vrow + quad * 8 + 4);
    short4v l1 = *(const short4v*)(vrow + 32 + quad * 8);
    short4v h1 = *(const short4v*)(vrow + 32 + quad * 8 + 4);
    short8 bv0 = __builtin_shufflevector(l0, h0, 0, 1, 2, 3, 4, 5, 6, 7);
    short8 bv1 = __builtin_shufflevector(l1, h1, 0, 1, 2, 3, 4, 5, 6, 7);
    f32x4 z = (f32x4){0.f, 0.f, 0.f, 0.f};
    z = __builtin_amdgcn_mfma_f32_16x16x32_bf16(ap0, bv0, z, 0, 0, 0);
    o[dt] = __builtin_amdgcn_mfma_f32_16x16x32_bf16(ap1, bv1, z, 0, 0, 0);
  }

  // ---- store (C-layout: col = d within tile, row = quad*4+r) ----
#pragma unroll
  for (int dt = 0; dt < 4; ++dt) {
#pragma unroll
    for (int r = 0; r < 4; ++r) {
      const int row = quad * 4 + r;
      if (row < nq)
        ctx[((long)b * 2048 + cs + row) * 1024 + h * 64 + dt * 16 + n] = f2bf(o[dt][r]);
    }
  }
}

extern "C" void kernel_launch(void* const* d_in, const int* in_sizes, int n_in,
                              void* d_out, int out_size, void* d_ws, size_t ws_size,
                              hipStream_t stream) {
  const float* X  = (const float*)d_in[0];
  const float* Wq = (const float*)d_in[1];
  const float* bq = (const float*)d_in[2];
  const float* Wk = (const float*)d_in[3];
  const float* bk = (const float*)d_in[4];
  const float* Wv = (const float*)d_in[5];
  const float* bv = (const float*)d_in[6];
  const float* Wo = (const float*)d_in[7];
  const float* bo = (const float*)d_in[8];
  float* out = (float*)d_out;

  char* ws = (char*)d_ws;
  u16* Xbf   = (u16*)(ws);                  // [4096,1024] bf16   8,388,608 B
  u16* Wcat  = (u16*)(ws + 8388608);        // [3072,1024] bf16   6,291,456 B
  u16* Wobf  = (u16*)(ws + 14680064);       // [1024,1024] bf16   2,097,152 B
  float* bcat = (float*)(ws + 16777216);    // [3072] f32            12,288 B
  u16* QKV   = (u16*)(ws + 16789504);       // [4096,3072] bf16  25,165,824 B
  u16* ctx   = (u16*)(ws + 41955328);       // [4096,1024] bf16   8,388,608 B

  pack_kernel<<<4098, 256, 0, stream>>>(X, Wq, bq, Wk, bk, Wv, bv, Wo, Xbf, Wcat, Wobf, bcat);
  gemm_bt<true ><<<dim3(32, 24), 256, 0, stream>>>(Xbf, Wcat, bcat, QKV, nullptr, 4096, 3072, 1024);
  attn_kernel<<<1640, 256, 0, stream>>>(QKV, ctx);
  gemm_bt<false><<<dim3(32, 8), 256, 0, stream>>>(ctx, Wobf, bo, nullptr, out, 4096, 1024, 1024);
}